// Round 2
// baseline (938.617 us; speedup 1.0000x reference)
//
#include <hip/hip_runtime.h>
#include <stdint.h>

typedef unsigned short u16;
typedef __bf16 bf16x8 __attribute__((ext_vector_type(8)));
typedef float f32x4 __attribute__((ext_vector_type(4)));

#define N_NODES 50000
#define N_EDGES 800000
#define LN_EPS 1e-5f

__device__ __forceinline__ float bf2f(u16 u) {
    union { unsigned int i; float f; } c; c.i = ((unsigned int)u) << 16; return c.f;
}
__device__ __forceinline__ u16 f2bf(float f) {
    union { float f; unsigned int i; } c; c.f = f;
    unsigned int r = c.i + 0x7FFFu + ((c.i >> 16) & 1u);
    return (u16)(r >> 16);
}
// pack 8 consecutive f32 -> uint4 of 8 bf16
__device__ __forceinline__ uint4 pack8(const float* __restrict__ p) {
    const float4 f0 = ((const float4*)p)[0];
    const float4 f1 = ((const float4*)p)[1];
    union { u16 u[8]; uint4 q; } t;
    t.u[0] = f2bf(f0.x); t.u[1] = f2bf(f0.y); t.u[2] = f2bf(f0.z); t.u[3] = f2bf(f0.w);
    t.u[4] = f2bf(f1.x); t.u[5] = f2bf(f1.y); t.u[6] = f2bf(f1.z); t.u[7] = f2bf(f1.w);
    return t.q;
}

// Load per-wave B-fragments for W[K][128] row-major f32: lane holds
// W[kb*32 + (lane>>4)*8 + j][n_base + n*16 + (lane&15)], j=0..7 (bf16).
template<int KB>
__device__ __forceinline__ void load_wfrag(const float* __restrict__ W, int n_base, int lane,
                                           bf16x8 (&wf)[KB][2]) {
    const int kq = (lane >> 4) * 8;
    const int cl = lane & 15;
#pragma unroll
    for (int kb = 0; kb < KB; ++kb) {
#pragma unroll
        for (int n = 0; n < 2; ++n) {
            const float* p = W + (size_t)(kb * 32 + kq) * 128 + (n_base + n * 16 + cl);
            union { u16 u[8]; bf16x8 v; } t;
#pragma unroll
            for (int j = 0; j < 8; ++j) t.u[j] = f2bf(p[j * 128]);
            wf[kb][n] = t.v;
        }
    }
}

// ---------------- Edge MLP + scatter-add ----------------
// x tile: [part(0=send,1=recv,2=elat)][64 rows][128 bf16], 16B chunks,
// XOR-swizzled within each row: stored_chunk = chunk ^ (row&7).
__global__ __launch_bounds__(256, 2)
void edge_mlp_kernel(const float* __restrict__ node, const float* __restrict__ elat,
                     const int* __restrict__ senders, const int* __restrict__ receivers,
                     const float* __restrict__ w1, const float* __restrict__ b1,
                     const float* __restrict__ w2, const float* __restrict__ b2,
                     const float* __restrict__ gam, const float* __restrict__ bet,
                     float* __restrict__ eout, float* __restrict__ aggr)
{
    __shared__ __align__(16) u16 x_lds[3 * 64 * 128];   // 48 KB
    __shared__ __align__(16) u16 h_lds[64 * 128];       // 16 KB (h1)

    // LN scratch overlaid into part-0 region of x_lds (dead after layer 1).
    float2* part = (float2*)x_lds;            // 256 float2, bytes [0,2048)
    float* muv = (float*)(x_lds + 1024);      // bytes [2048,2304)
    float* rsv = (float*)(x_lds + 1152);      // bytes [2304,2560)

    const int tid = threadIdx.x;
    const int w = tid >> 6;
    const int lane = tid & 63;
    const int cl = lane & 15;
    const int q = lane >> 4;
    const int n_base = w * 32;

    bf16x8 w1f[12][2], w2f[4][2];
    load_wfrag<12>(w1, n_base, lane, w1f);
    load_wfrag<4>(w2, n_base, lane, w2f);
    float b1v[2], b2v[2], gv[2], bv[2];
#pragma unroll
    for (int n = 0; n < 2; ++n) {
        const int c = n_base + n * 16 + cl;
        b1v[n] = b1[c]; b2v[n] = b2[c];
        gv[n]  = gam[c]; bv[n] = bet[c];
    }

    for (int tile = blockIdx.x; tile < N_EDGES / 64; tile += gridDim.x) {
        const int base = tile * 64;

        // ---- gather + f32->bf16 convert: 16 rows x 16 chunk-lanes per pass ----
        {
            const int ch = tid & 15;
            const int r0 = tid >> 4;
#pragma unroll
            for (int gp = 0; gp < 4; ++gp) {
                const int row = gp * 16 + r0;
                const int rx = row & 7;
                const int sn = senders[base + row];
                const int rc = receivers[base + row];
                uint4* dst = (uint4*)x_lds + row * 16;
                dst[(ch ^ rx)]        = pack8(node + (size_t)sn * 128 + ch * 8);
                dst[1024 + (ch ^ rx)] = pack8(node + (size_t)rc * 128 + ch * 8);
                dst[2048 + (ch ^ rx)] = pack8(elat + (size_t)(base + row) * 128 + ch * 8);
            }
        }
        __syncthreads();

        // ---- layer 1: [64,384] x [384,128] ----
        f32x4 acc[4][2];
#pragma unroll
        for (int m = 0; m < 4; ++m)
#pragma unroll
            for (int n = 0; n < 2; ++n)
#pragma unroll
                for (int r = 0; r < 4; ++r) acc[m][n][r] = 0.f;

#pragma unroll
        for (int kb = 0; kb < 12; ++kb) {
            const int p = kb >> 2, k2 = kb & 3;
            bf16x8 a[4];
#pragma unroll
            for (int m = 0; m < 4; ++m) {
                const int row = m * 16 + cl;
                a[m] = __builtin_bit_cast(bf16x8,
                    ((const uint4*)x_lds)[p * 1024 + row * 16 + ((k2 * 4 + q) ^ (row & 7))]);
            }
#pragma unroll
            for (int m = 0; m < 4; ++m)
#pragma unroll
                for (int n = 0; n < 2; ++n)
                    acc[m][n] = __builtin_amdgcn_mfma_f32_16x16x32_bf16(a[m], w1f[kb][n], acc[m][n], 0, 0, 0);
        }

        // relu + bias, h1 -> LDS (swizzled)
#pragma unroll
        for (int m = 0; m < 4; ++m)
#pragma unroll
            for (int n = 0; n < 2; ++n)
#pragma unroll
                for (int r = 0; r < 4; ++r) {
                    const int row = m * 16 + q * 4 + r;
                    const int col = n_base + n * 16 + cl;
                    const float v = fmaxf(acc[m][n][r] + b1v[n], 0.f);
                    h_lds[row * 128 + (((col >> 3) ^ (row & 7)) << 3) + (col & 7)] = f2bf(v);
                }
        __syncthreads();

        // ---- layer 2: [64,128] x [128,128] ----
#pragma unroll
        for (int m = 0; m < 4; ++m)
#pragma unroll
            for (int n = 0; n < 2; ++n)
#pragma unroll
                for (int r = 0; r < 4; ++r) acc[m][n][r] = 0.f;
#pragma unroll
        for (int kb = 0; kb < 4; ++kb) {
            bf16x8 a[4];
#pragma unroll
            for (int m = 0; m < 4; ++m) {
                const int row = m * 16 + cl;
                a[m] = __builtin_bit_cast(bf16x8,
                    ((const uint4*)h_lds)[row * 16 + ((kb * 4 + q) ^ (row & 7))]);
            }
#pragma unroll
            for (int m = 0; m < 4; ++m)
#pragma unroll
                for (int n = 0; n < 2; ++n)
                    acc[m][n] = __builtin_amdgcn_mfma_f32_16x16x32_bf16(a[m], w2f[kb][n], acc[m][n], 0, 0, 0);
        }

        // relu + bias in place
#pragma unroll
        for (int m = 0; m < 4; ++m)
#pragma unroll
            for (int n = 0; n < 2; ++n)
#pragma unroll
                for (int r = 0; r < 4; ++r)
                    acc[m][n][r] = fmaxf(acc[m][n][r] + b2v[n], 0.f);

        // per-row partial sums (each wave covers 32 cols of every row)
#pragma unroll
        for (int m = 0; m < 4; ++m)
#pragma unroll
            for (int r = 0; r < 4; ++r) {
                float s  = acc[m][0][r] + acc[m][1][r];
                float ss = acc[m][0][r] * acc[m][0][r] + acc[m][1][r] * acc[m][1][r];
#pragma unroll
                for (int off = 1; off < 16; off <<= 1) {
                    s  += __shfl_xor(s, off, 64);
                    ss += __shfl_xor(ss, off, 64);
                }
                if (cl == 0) part[w * 64 + m * 16 + q * 4 + r] = make_float2(s, ss);
            }
        __syncthreads();
        if (tid < 64) {
            float s = 0.f, ss = 0.f;
#pragma unroll
            for (int ww = 0; ww < 4; ++ww) { const float2 pp = part[ww * 64 + tid]; s += pp.x; ss += pp.y; }
            const float mu = s * (1.f / 128.f);
            const float var = ss * (1.f / 128.f) - mu * mu;
            muv[tid] = mu;
            rsv[tid] = rsqrtf(var + LN_EPS);
        }
        __syncthreads();

        // ---- LN + scatter atomics + residual + direct f32 writeout ----
#pragma unroll
        for (int m = 0; m < 4; ++m)
#pragma unroll
            for (int r = 0; r < 4; ++r) {
                const int row = m * 16 + q * 4 + r;
                const float mu = muv[row];
                const float rs = rsv[row];
                const int rc = receivers[base + row];
                float* orow = eout + (size_t)(base + row) * 128;
#pragma unroll
                for (int n = 0; n < 2; ++n) {
                    const int col = n_base + n * 16 + cl;
                    const float ln = (acc[m][n][r] - mu) * rs * gv[n] + bv[n];
                    atomicAdd(&aggr[(size_t)rc * 128 + col], ln);
                    const float e = bf2f(x_lds[16384 + row * 128 + (((col >> 3) ^ (row & 7)) << 3) + (col & 7)]);
                    orow[col] = ln + e;
                }
            }
        __syncthreads();  // protect x_lds (elat residual + LN scratch) before next gather
    }
}

// ---------------- Node MLP ----------------
__global__ __launch_bounds__(256, 2)
void node_mlp_kernel(const float* __restrict__ node, const float* __restrict__ aggr,
                     const float* __restrict__ w1, const float* __restrict__ b1,
                     const float* __restrict__ w2, const float* __restrict__ b2,
                     const float* __restrict__ gam, const float* __restrict__ bet,
                     float* __restrict__ nout)
{
    __shared__ __align__(16) u16 x_lds[2 * 64 * 128];   // 32 KB: [0]=node, [1]=aggr
    __shared__ __align__(16) u16 h_lds[64 * 128];       // 16 KB
    __shared__ float2 part[256];
    __shared__ float muv[64], rsv[64];

    const int tid = threadIdx.x;
    const int w = tid >> 6;
    const int lane = tid & 63;
    const int cl = lane & 15;
    const int q = lane >> 4;
    const int n_base = w * 32;

    bf16x8 w1f[8][2], w2f[4][2];
    load_wfrag<8>(w1, n_base, lane, w1f);
    load_wfrag<4>(w2, n_base, lane, w2f);
    float b1v[2], b2v[2], gv[2], bv[2];
#pragma unroll
    for (int n = 0; n < 2; ++n) {
        const int c = n_base + n * 16 + cl;
        b1v[n] = b1[c]; b2v[n] = b2[c];
        gv[n]  = gam[c]; bv[n] = bet[c];
    }

    const int ntiles = (N_NODES + 63) / 64;
    for (int tile = blockIdx.x; tile < ntiles; tile += gridDim.x) {
        const int base = tile * 64;

        // ---- gather (contiguous rows; f32 -> bf16) ----
        {
            const int ch = tid & 15;
            const int r0 = tid >> 4;
#pragma unroll
            for (int gp = 0; gp < 4; ++gp) {
                const int row = gp * 16 + r0;
                const int rx = row & 7;
                int gn = base + row;
                if (gn >= N_NODES) gn = N_NODES - 1;
                uint4* dst = (uint4*)x_lds + row * 16;
                dst[(ch ^ rx)]        = pack8(node + (size_t)gn * 128 + ch * 8);
                dst[1024 + (ch ^ rx)] = pack8(aggr + (size_t)gn * 128 + ch * 8);
            }
        }
        __syncthreads();

        // ---- layer 1: [64,256] x [256,128] ----
        f32x4 acc[4][2];
#pragma unroll
        for (int m = 0; m < 4; ++m)
#pragma unroll
            for (int n = 0; n < 2; ++n)
#pragma unroll
                for (int r = 0; r < 4; ++r) acc[m][n][r] = 0.f;
#pragma unroll
        for (int kb = 0; kb < 8; ++kb) {
            const int p = kb >> 2, k2 = kb & 3;
            bf16x8 a[4];
#pragma unroll
            for (int m = 0; m < 4; ++m) {
                const int row = m * 16 + cl;
                a[m] = __builtin_bit_cast(bf16x8,
                    ((const uint4*)x_lds)[p * 1024 + row * 16 + ((k2 * 4 + q) ^ (row & 7))]);
            }
#pragma unroll
            for (int m = 0; m < 4; ++m)
#pragma unroll
                for (int n = 0; n < 2; ++n)
                    acc[m][n] = __builtin_amdgcn_mfma_f32_16x16x32_bf16(a[m], w1f[kb][n], acc[m][n], 0, 0, 0);
        }
#pragma unroll
        for (int m = 0; m < 4; ++m)
#pragma unroll
            for (int n = 0; n < 2; ++n)
#pragma unroll
                for (int r = 0; r < 4; ++r) {
                    const int row = m * 16 + q * 4 + r;
                    const int col = n_base + n * 16 + cl;
                    const float v = fmaxf(acc[m][n][r] + b1v[n], 0.f);
                    h_lds[row * 128 + (((col >> 3) ^ (row & 7)) << 3) + (col & 7)] = f2bf(v);
                }
        __syncthreads();

        // ---- layer 2 ----
#pragma unroll
        for (int m = 0; m < 4; ++m)
#pragma unroll
            for (int n = 0; n < 2; ++n)
#pragma unroll
                for (int r = 0; r < 4; ++r) acc[m][n][r] = 0.f;
#pragma unroll
        for (int kb = 0; kb < 4; ++kb) {
            bf16x8 a[4];
#pragma unroll
            for (int m = 0; m < 4; ++m) {
                const int row = m * 16 + cl;
                a[m] = __builtin_bit_cast(bf16x8,
                    ((const uint4*)h_lds)[row * 16 + ((kb * 4 + q) ^ (row & 7))]);
            }
#pragma unroll
            for (int m = 0; m < 4; ++m)
#pragma unroll
                for (int n = 0; n < 2; ++n)
                    acc[m][n] = __builtin_amdgcn_mfma_f32_16x16x32_bf16(a[m], w2f[kb][n], acc[m][n], 0, 0, 0);
        }
#pragma unroll
        for (int m = 0; m < 4; ++m)
#pragma unroll
            for (int n = 0; n < 2; ++n)
#pragma unroll
                for (int r = 0; r < 4; ++r)
                    acc[m][n][r] = fmaxf(acc[m][n][r] + b2v[n], 0.f);

#pragma unroll
        for (int m = 0; m < 4; ++m)
#pragma unroll
            for (int r = 0; r < 4; ++r) {
                float s  = acc[m][0][r] + acc[m][1][r];
                float ss = acc[m][0][r] * acc[m][0][r] + acc[m][1][r] * acc[m][1][r];
#pragma unroll
                for (int off = 1; off < 16; off <<= 1) {
                    s  += __shfl_xor(s, off, 64);
                    ss += __shfl_xor(ss, off, 64);
                }
                if (cl == 0) part[w * 64 + m * 16 + q * 4 + r] = make_float2(s, ss);
            }
        __syncthreads();
        if (tid < 64) {
            float s = 0.f, ss = 0.f;
#pragma unroll
            for (int ww = 0; ww < 4; ++ww) { const float2 pp = part[ww * 64 + tid]; s += pp.x; ss += pp.y; }
            const float mu = s * (1.f / 128.f);
            const float var = ss * (1.f / 128.f) - mu * mu;
            muv[tid] = mu;
            rsv[tid] = rsqrtf(var + LN_EPS);
        }
        __syncthreads();

        // ---- LN + residual(node latents) + guarded f32 writeout ----
#pragma unroll
        for (int m = 0; m < 4; ++m)
#pragma unroll
            for (int r = 0; r < 4; ++r) {
                const int row = m * 16 + q * 4 + r;
                if (base + row < N_NODES) {
                    const float mu = muv[row];
                    const float rs = rsv[row];
                    float* orow = nout + (size_t)(base + row) * 128;
#pragma unroll
                    for (int n = 0; n < 2; ++n) {
                        const int col = n_base + n * 16 + cl;
                        const float ln = (acc[m][n][r] - mu) * rs * gv[n] + bv[n];
                        const float e = bf2f(x_lds[row * 128 + (((col >> 3) ^ (row & 7)) << 3) + (col & 7)]);
                        orow[col] = ln + e;
                    }
                }
            }
        __syncthreads();  // protect x_lds before next gather
    }
}

extern "C" void kernel_launch(void* const* d_in, const int* in_sizes, int n_in,
                              void* d_out, int out_size, void* d_ws, size_t ws_size,
                              hipStream_t stream) {
    (void)in_sizes; (void)n_in; (void)out_size;
    const float* node = (const float*)d_in[0];
    const float* elat = (const float*)d_in[1];
    const int* senders = (const int*)d_in[2];
    const int* receivers = (const int*)d_in[3];
    const float* me_w1 = (const float*)d_in[4];
    const float* me_b1 = (const float*)d_in[5];
    const float* me_w2 = (const float*)d_in[6];
    const float* me_b2 = (const float*)d_in[7];
    const float* me_g  = (const float*)d_in[8];
    const float* me_be = (const float*)d_in[9];
    const float* nf_w1 = (const float*)d_in[10];
    const float* nf_b1 = (const float*)d_in[11];
    const float* nf_w2 = (const float*)d_in[12];
    const float* nf_b2 = (const float*)d_in[13];
    const float* nf_g  = (const float*)d_in[14];
    const float* nf_be = (const float*)d_in[15];

    float* out_nodes = (float*)d_out;
    float* out_edges = out_nodes + (size_t)N_NODES * 128;
    float* aggr = (float*)d_ws;
    const size_t aggr_bytes = (size_t)N_NODES * 128 * sizeof(float);
    if (ws_size < aggr_bytes) return;

    hipMemsetAsync(aggr, 0, aggr_bytes, stream);
    edge_mlp_kernel<<<512, 256, 0, stream>>>(node, elat, senders, receivers,
                                             me_w1, me_b1, me_w2, me_b2, me_g, me_be,
                                             out_edges, aggr);
    node_mlp_kernel<<<782, 256, 0, stream>>>(node, aggr,
                                             nf_w1, nf_b1, nf_w2, nf_b2, nf_g, nf_be,
                                             out_nodes);
}